// Round 4
// baseline (252.358 us; speedup 1.0000x reference)
//
#include <hip/hip_runtime.h>
#include <hip/hip_bf16.h>
#include <stdint.h>

// Problem: N=4096 rows, D=768 dims.
//   dist[i][j] = ||A_i - P_j||;  scores = 50 - dist;  loss = mean_i(-log_softmax(scores)_ii)
// Fixed-shift softmax (scores <= 50 always): loss_i = dist_ii + log(sum_j exp(-dist_ij))

#define N_ROWS 4096
#define D_DIM  768
#define GRID_DIM (N_ROWS / 128)          // 32
#define TOTAL_BLOCKS (GRID_DIM * GRID_DIM)

typedef float f32x4 __attribute__((ext_vector_type(4)));
typedef short bf16x8 __attribute__((ext_vector_type(8)));   // 8 bf16 in 4 VGPRs

struct bh4 { __hip_bfloat16 a, b, c, d; };  // 8-byte packed bf16 store

// ---------------- kernel 1: fp32 -> bf16 cast + row norms + zero S/ticket --------
__global__ __launch_bounds__(256) void cvt_norms(
        const float* __restrict__ A, const float* __restrict__ P,
        __hip_bfloat16* __restrict__ Ab, __hip_bfloat16* __restrict__ Pb,
        float* __restrict__ a2, float* __restrict__ p2, float* __restrict__ S,
        int* __restrict__ ticket) {
    const int t = threadIdx.x, lane = t & 63, wave = t >> 6;
    const int row = blockIdx.x * 4 + wave;
    const float* src = blockIdx.y ? P : A;
    __hip_bfloat16* dst = blockIdx.y ? Pb : Ab;
    float* nrm = blockIdx.y ? p2 : a2;

    const float4* s4 = (const float4*)src + (size_t)row * (D_DIM / 4);
    bh4* d4 = (bh4*)dst + (size_t)row * (D_DIM / 4);
    float s = 0.0f;
#pragma unroll
    for (int c = 0; c < 3; c++) {
        float4 v = s4[c * 64 + lane];
        s += v.x * v.x + v.y * v.y + v.z * v.z + v.w * v.w;
        bh4 o;
        o.a = __float2bfloat16(v.x); o.b = __float2bfloat16(v.y);
        o.c = __float2bfloat16(v.z); o.d = __float2bfloat16(v.w);
        d4[c * 64 + lane] = o;
    }
    for (int off = 32; off; off >>= 1) s += __shfl_down(s, off);
    if (lane == 0) {
        nrm[row] = s;
        if (blockIdx.y == 0) S[row] = 0.0f;
    }
    if (blockIdx.x == 0 && blockIdx.y == 0 && t == 0) *ticket = 0;
}

// ---------------- kernel 2: barrier-free bf16 MFMA GEMM + softmax epilogue -------
// 128x128 C-tile / 256-thread block (2x2 waves, 64x64 each). NO LDS: MFMA A/B
// fragments are loaded straight from row-major global (each 64-lane bf16x8 load
// = 16 rows x 64B contiguous, fully used). No __syncthreads in the K-loop; VMEM
// latency hidden by unrolled prefetch + multi-wave occupancy.
__global__ __launch_bounds__(256) void gemm_fused(
        const __hip_bfloat16* __restrict__ Ab, const __hip_bfloat16* __restrict__ Pb,
        const float* __restrict__ a2, const float* __restrict__ p2,
        float* __restrict__ S, float* __restrict__ Dd,
        int* __restrict__ ticket, float* __restrict__ out) {
    const int bm = blockIdx.x, bn = blockIdx.y;
    const int t = threadIdx.x;
    const int lane = t & 63, wave = t >> 6;
    const int wm = wave >> 1, wn = wave & 1;
    const int fr = lane & 15, fq = lane >> 4;

    // fragment base offsets (bf16 elements): row = tile_row + fr, k-chunk = fq*8
    const __hip_bfloat16* aB = Ab + (size_t)(bm * 128 + wm * 64 + fr) * D_DIM + fq * 8;
    const __hip_bfloat16* bB = Pb + (size_t)(bn * 128 + wn * 64 + fr) * D_DIM + fq * 8;

    f32x4 acc[4][4];
#pragma unroll
    for (int i = 0; i < 4; i++)
#pragma unroll
        for (int j = 0; j < 4; j++) acc[i][j] = (f32x4){0.f, 0.f, 0.f, 0.f};

#pragma unroll 4
    for (int ks = 0; ks < D_DIM / 32; ks++) {
        bf16x8 af[4], bfr[4];
#pragma unroll
        for (int mi = 0; mi < 4; mi++)
            af[mi] = *(const bf16x8*)(aB + mi * (16 * D_DIM) + ks * 32);
#pragma unroll
        for (int ni = 0; ni < 4; ni++)
            bfr[ni] = *(const bf16x8*)(bB + ni * (16 * D_DIM) + ks * 32);
#pragma unroll
        for (int mi = 0; mi < 4; mi++)
#pragma unroll
            for (int ni = 0; ni < 4; ni++)
                acc[mi][ni] = __builtin_amdgcn_mfma_f32_16x16x32_bf16(
                    af[mi], bfr[ni], acc[mi][ni], 0, 0, 0);
    }

    // ---- epilogue: dist -> exp(-dist), per-row partial sums, diagonal capture ----
    // C/D layout (16x16x32 bf16): col = lane&15, row = (lane>>4)*4 + reg
    float p2v[4];
#pragma unroll
    for (int ni = 0; ni < 4; ni++)
        p2v[ni] = p2[bn * 128 + wn * 64 + ni * 16 + (lane & 15)];
    const int colBase = bn * 128 + wn * 64 + (lane & 15);

#pragma unroll
    for (int mi = 0; mi < 4; mi++) {
#pragma unroll
        for (int r = 0; r < 4; r++) {
            const int gi = bm * 128 + wm * 64 + mi * 16 + (lane >> 4) * 4 + r;
            const float a2v = a2[gi];
            float rs = 0.0f;
#pragma unroll
            for (int ni = 0; ni < 4; ni++) {
                const float cross = acc[mi][ni][r];
                const float sq = a2v + p2v[ni] - 2.0f * cross;
                const float dist = sqrtf(fmaxf(sq, 0.0f) + 1e-12f);
                const int gj = colBase + ni * 16;
                if (gi == gj)
                    __hip_atomic_store(&Dd[gi], dist, __ATOMIC_RELAXED,
                                       __HIP_MEMORY_SCOPE_AGENT);
                rs += __expf(-dist);
            }
            rs += __shfl_xor(rs, 1);
            rs += __shfl_xor(rs, 2);
            rs += __shfl_xor(rs, 4);
            rs += __shfl_xor(rs, 8);
            if ((lane & 15) == 0) atomicAdd(&S[gi], rs);
        }
    }

    // ---- last-block finalize ----
    __threadfence();                       // release S/Dd before ticket
    __shared__ int lastFlag;
    if (t == 0) lastFlag = (atomicAdd(ticket, 1) == TOTAL_BLOCKS - 1);
    __syncthreads();
    if (lastFlag) {
        __threadfence();                   // acquire: others' S/Dd now visible
        float s = 0.0f;
        for (int i = t; i < N_ROWS; i += 256) {
            float Sv = __hip_atomic_load(&S[i], __ATOMIC_RELAXED, __HIP_MEMORY_SCOPE_AGENT);
            float Dv = __hip_atomic_load(&Dd[i], __ATOMIC_RELAXED, __HIP_MEMORY_SCOPE_AGENT);
            s += Dv + logf(Sv);
        }
        for (int off = 32; off; off >>= 1) s += __shfl_down(s, off);
        __shared__ float wsum[4];
        if ((t & 63) == 0) wsum[t >> 6] = s;
        __syncthreads();
        if (t == 0) out[0] = (wsum[0] + wsum[1] + wsum[2] + wsum[3]) * (1.0f / N_ROWS);
    }
}

// ---------------- fallback (undersized workspace): naive fp32 --------------------
__global__ void zero_out1(float* __restrict__ out) {
    if (threadIdx.x == 0 && blockIdx.x == 0) out[0] = 0.0f;
}
__global__ void naive_row(const float* __restrict__ A, const float* __restrict__ P,
                          float* __restrict__ out) {
    __shared__ float arow[D_DIM];
    const int i = blockIdx.x, t = threadIdx.x;
    for (int c = t; c < D_DIM; c += 256) arow[c] = A[(size_t)i * D_DIM + c];
    __syncthreads();
    float sumexp = 0.0f, ddiag = 0.0f;
    for (int j = t; j < N_ROWS; j += 256) {
        const float* p = P + (size_t)j * D_DIM;
        float d2 = 0.0f;
        for (int c = 0; c < D_DIM; c++) { float df = arow[c] - p[c]; d2 += df * df; }
        float dist = sqrtf(fmaxf(d2, 0.0f) + 1e-12f);
        if (j == i) ddiag = dist;
        sumexp += __expf(-dist);
    }
    for (int off = 32; off; off >>= 1) {
        sumexp += __shfl_down(sumexp, off);
        ddiag  += __shfl_down(ddiag, off);
    }
    __shared__ float w1[4], w2[4];
    if ((t & 63) == 0) { w1[t >> 6] = sumexp; w2[t >> 6] = ddiag; }
    __syncthreads();
    if (t == 0) {
        float se = w1[0] + w1[1] + w1[2] + w1[3];
        float dd = w2[0] + w2[1] + w2[2] + w2[3];
        atomicAdd(out, (dd + logf(se)) * (1.0f / N_ROWS));
    }
}

extern "C" void kernel_launch(void* const* d_in, const int* in_sizes, int n_in,
                              void* d_out, int out_size, void* d_ws, size_t ws_size,
                              hipStream_t stream) {
    const float* A = (const float*)d_in[0];
    const float* P = (const float*)d_in[1];
    float* out = (float*)d_out;

    const size_t BF_BYTES = (size_t)N_ROWS * D_DIM * sizeof(__hip_bfloat16); // 6291456
    const size_t V_BYTES  = (size_t)N_ROWS * sizeof(float);                  // 16384
    const size_t NEED = 2 * BF_BYTES + 4 * V_BYTES + 256;

    if (ws_size >= NEED) {
        char* ws = (char*)d_ws;
        __hip_bfloat16* Ab = (__hip_bfloat16*)(ws);
        __hip_bfloat16* Pb = (__hip_bfloat16*)(ws + BF_BYTES);
        float* a2 = (float*)(ws + 2 * BF_BYTES);
        float* p2 = (float*)(ws + 2 * BF_BYTES + V_BYTES);
        float* S  = (float*)(ws + 2 * BF_BYTES + 2 * V_BYTES);
        float* Dd = (float*)(ws + 2 * BF_BYTES + 3 * V_BYTES);
        int* ticket = (int*)(ws + 2 * BF_BYTES + 4 * V_BYTES);

        hipLaunchKernelGGL(cvt_norms, dim3(N_ROWS / 4, 2), dim3(256), 0, stream,
                           A, P, Ab, Pb, a2, p2, S, ticket);
        hipLaunchKernelGGL(gemm_fused, dim3(GRID_DIM, GRID_DIM), dim3(256), 0, stream,
                           Ab, Pb, a2, p2, S, Dd, ticket, out);
    } else {
        hipLaunchKernelGGL(zero_out1, dim3(1), dim3(64), 0, stream, out);
        hipLaunchKernelGGL(naive_row, dim3(N_ROWS), dim3(256), 0, stream, A, P, out);
    }
}

// Round 5
// 121.069 us; speedup vs baseline: 2.0844x; 2.0844x over previous
//
#include <hip/hip_runtime.h>
#include <hip/hip_bf16.h>
#include <stdint.h>

// Problem: N=4096 rows, D=768 dims.
//   dist[i][j] = ||A_i - P_j||;  scores = 50 - dist;  loss = mean_i(-log_softmax(scores)_ii)
// Fixed-shift softmax (scores <= 50 always): loss_i = dist_ii + log(sum_j exp(-dist_ij))

#define N_ROWS 4096
#define D_DIM  768
#define GRID_DIM (N_ROWS / 128)          // 32
#define NITER (D_DIM / 64)               // 12

typedef float f32x4 __attribute__((ext_vector_type(4)));
typedef short bf16x8 __attribute__((ext_vector_type(8)));   // 8 bf16 in 4 VGPRs

struct bh4 { __hip_bfloat16 a, b, c, d; };  // 8-byte packed bf16 store

// ---------------- kernel 1: fp32 -> bf16 cast + row norms + zero S ---------------
__global__ __launch_bounds__(256) void cvt_norms(
        const float* __restrict__ A, const float* __restrict__ P,
        __hip_bfloat16* __restrict__ Ab, __hip_bfloat16* __restrict__ Pb,
        float* __restrict__ a2, float* __restrict__ p2, float* __restrict__ S) {
    const int t = threadIdx.x, lane = t & 63, wave = t >> 6;
    const int row = blockIdx.x * 4 + wave;
    const float* src = blockIdx.y ? P : A;
    __hip_bfloat16* dst = blockIdx.y ? Pb : Ab;
    float* nrm = blockIdx.y ? p2 : a2;

    const float4* s4 = (const float4*)src + (size_t)row * (D_DIM / 4);
    bh4* d4 = (bh4*)dst + (size_t)row * (D_DIM / 4);
    float s = 0.0f;
#pragma unroll
    for (int c = 0; c < 3; c++) {
        float4 v = s4[c * 64 + lane];
        s += v.x * v.x + v.y * v.y + v.z * v.z + v.w * v.w;
        bh4 o;
        o.a = __float2bfloat16(v.x); o.b = __float2bfloat16(v.y);
        o.c = __float2bfloat16(v.z); o.d = __float2bfloat16(v.w);
        d4[c * 64 + lane] = o;
    }
    for (int off = 32; off; off >>= 1) s += __shfl_down(s, off);
    if (lane == 0) {
        nrm[row] = s;
        if (blockIdx.y == 0) S[row] = 0.0f;
    }
}

// ---------------- kernel 2: double-buffered bf16 MFMA GEMM + softmax epilogue ----
// 128x128 C-tile / 256-thread block (2x2 waves, 64x64 each), BK=64, XOR-swizzled
// LDS (conflict-free). TRUE software pipeline: raw s_barrier + s_waitcnt vmcnt(8)
// (never a full drain except the last iter) so each tile's global_load_lds stays
// in flight for a whole iteration of MFMA cover — the hipBLASLt-style K-loop the
// __syncthreads() structure cannot express.
__device__ __forceinline__ void g2l16(const void* g, void* l) {
    __builtin_amdgcn_global_load_lds(
        (const __attribute__((address_space(1))) void*)g,
        (__attribute__((address_space(3))) void*)l, 16, 0, 0);
}

__global__ __launch_bounds__(256) void gemm_fused(
        const __hip_bfloat16* __restrict__ Ab, const __hip_bfloat16* __restrict__ Pb,
        const float* __restrict__ a2, const float* __restrict__ p2,
        float* __restrict__ S, float* __restrict__ Dd) {
    __shared__ __align__(16) unsigned short As[2][128 * 64];   // 2 x 16 KB
    __shared__ __align__(16) unsigned short Bs[2][128 * 64];   // 2 x 16 KB

    const int bm = blockIdx.x, bn = blockIdx.y;
    const int t = threadIdx.x;
    const int lane = t & 63, wave = t >> 6;
    const int wm = wave >> 1, wn = wave & 1;

    f32x4 acc[4][4];
#pragma unroll
    for (int i = 0; i < 4; i++)
#pragma unroll
        for (int j = 0; j < 4; j++) acc[i][j] = (f32x4){0.f, 0.f, 0.f, 0.f};

    // staging: physical chunk p = c*256+t holds global row r = c*32 + (t>>3),
    // chunk sg = (t&7) ^ ((t>>3)&7)  (c-independent since c*32 % 8 == 0).
    const int rT = t >> 3;
    const int sg = (t & 7) ^ (rT & 7);
    const size_t aBase = (size_t)(bm * 128 + rT) * D_DIM + sg * 8;
    const size_t bBase = (size_t)(bn * 128 + rT) * D_DIM + sg * 8;

    // LDS->frag read indices (shorts). row stride 64 shorts (128B).
    const int fr = lane & 15, fq = lane >> 4;
    const int xr = fr & 7;
    const int aRow = (wm * 64 + fr) * 64;
    const int bRow = (wn * 64 + fr) * 64;

#define STAGE(K2, SEL)                                                          \
    do {                                                                        \
        const int k0_ = (K2) * 64;                                              \
        _Pragma("unroll")                                                       \
        for (int c = 0; c < 4; c++)                                             \
            g2l16(Ab + aBase + c * (32 * D_DIM) + k0_, &As[SEL][(c * 256 + t) * 8]); \
        _Pragma("unroll")                                                       \
        for (int c = 0; c < 4; c++)                                             \
            g2l16(Pb + bBase + c * (32 * D_DIM) + k0_, &Bs[SEL][(c * 256 + t) * 8]); \
    } while (0)

    STAGE(0, 0);
    STAGE(1, 1);

    for (int k = 0; k < NITER; k++) {
        const int cur = k & 1;
        // tile k's 8 loads were issued >=1 iteration ago; newest 8 (tile k+1) may fly on.
        if (k == NITER - 1) asm volatile("s_waitcnt vmcnt(0)" ::: "memory");
        else                asm volatile("s_waitcnt vmcnt(8)" ::: "memory");
        asm volatile("s_barrier" ::: "memory");   // buf[cur] ready for everyone

#pragma unroll
        for (int tt = 0; tt < 2; tt++) {
            const int vA = (((tt << 2) | fq) ^ xr) * 8;
            bf16x8 af[4], bfr[4];
#pragma unroll
            for (int mi = 0; mi < 4; mi++)
                af[mi] = *(const bf16x8*)(As[cur] + aRow + mi * 1024 + vA);
#pragma unroll
            for (int ni = 0; ni < 4; ni++)
                bfr[ni] = *(const bf16x8*)(Bs[cur] + bRow + ni * 1024 + vA);
#pragma unroll
            for (int mi = 0; mi < 4; mi++)
#pragma unroll
                for (int ni = 0; ni < 4; ni++)
                    acc[mi][ni] = __builtin_amdgcn_mfma_f32_16x16x32_bf16(
                        af[mi], bfr[ni], acc[mi][ni], 0, 0, 0);
        }

        if (k + 2 < NITER) {
            asm volatile("s_barrier" ::: "memory");   // all waves done reading buf[cur]
            STAGE(k + 2, cur);
        }
    }
#undef STAGE

    // ---- epilogue: dist -> exp(-dist), per-row partial sums, diagonal capture ----
    // C/D layout (16x16x32 bf16): col = lane&15, row = (lane>>4)*4 + reg
    float p2v[4];
#pragma unroll
    for (int ni = 0; ni < 4; ni++)
        p2v[ni] = p2[bn * 128 + wn * 64 + ni * 16 + (lane & 15)];
    const int colBase = bn * 128 + wn * 64 + (lane & 15);

#pragma unroll
    for (int mi = 0; mi < 4; mi++) {
#pragma unroll
        for (int r = 0; r < 4; r++) {
            const int gi = bm * 128 + wm * 64 + mi * 16 + (lane >> 4) * 4 + r;
            const float a2v = a2[gi];
            float rs = 0.0f;
#pragma unroll
            for (int ni = 0; ni < 4; ni++) {
                const float cross = acc[mi][ni][r];
                const float sq = a2v + p2v[ni] - 2.0f * cross;
                const float dist = sqrtf(fmaxf(sq, 0.0f) + 1e-12f);
                const int gj = colBase + ni * 16;
                if (gi == gj) Dd[gi] = dist;
                rs += __expf(-dist);
            }
            rs += __shfl_xor(rs, 1);
            rs += __shfl_xor(rs, 2);
            rs += __shfl_xor(rs, 4);
            rs += __shfl_xor(rs, 8);
            if ((lane & 15) == 0) atomicAdd(&S[gi], rs);
        }
    }
}

// ---------------- kernel 3: final reduce -> scalar -------------------------------
__global__ void finalize(const float* __restrict__ S, const float* __restrict__ Dd,
                         float* __restrict__ out) {
    const int t = threadIdx.x;
    float s = 0.0f;
    for (int i = t; i < N_ROWS; i += 256) s += Dd[i] + logf(S[i]);
    for (int off = 32; off; off >>= 1) s += __shfl_down(s, off);
    __shared__ float wsum[4];
    if ((t & 63) == 0) wsum[t >> 6] = s;
    __syncthreads();
    if (t == 0) out[0] = (wsum[0] + wsum[1] + wsum[2] + wsum[3]) * (1.0f / N_ROWS);
}

// ---------------- fallback (undersized workspace): naive fp32 --------------------
__global__ void zero_out1(float* __restrict__ out) {
    if (threadIdx.x == 0 && blockIdx.x == 0) out[0] = 0.0f;
}
__global__ void naive_row(const float* __restrict__ A, const float* __restrict__ P,
                          float* __restrict__ out) {
    __shared__ float arow[D_DIM];
    const int i = blockIdx.x, t = threadIdx.x;
    for (int c = t; c < D_DIM; c += 256) arow[c] = A[(size_t)i * D_DIM + c];
    __syncthreads();
    float sumexp = 0.0f, ddiag = 0.0f;
    for (int j = t; j < N_ROWS; j += 256) {
        const float* p = P + (size_t)j * D_DIM;
        float d2 = 0.0f;
        for (int c = 0; c < D_DIM; c++) { float df = arow[c] - p[c]; d2 += df * df; }
        float dist = sqrtf(fmaxf(d2, 0.0f) + 1e-12f);
        if (j == i) ddiag = dist;
        sumexp += __expf(-dist);
    }
    for (int off = 32; off; off >>= 1) {
        sumexp += __shfl_down(sumexp, off);
        ddiag  += __shfl_down(ddiag, off);
    }
    __shared__ float w1[4], w2[4];
    if ((t & 63) == 0) { w1[t >> 6] = sumexp; w2[t >> 6] = ddiag; }
    __syncthreads();
    if (t == 0) {
        float se = w1[0] + w1[1] + w1[2] + w1[3];
        float dd = w2[0] + w2[1] + w2[2] + w2[3];
        atomicAdd(out, (dd + logf(se)) * (1.0f / N_ROWS));
    }
}

extern "C" void kernel_launch(void* const* d_in, const int* in_sizes, int n_in,
                              void* d_out, int out_size, void* d_ws, size_t ws_size,
                              hipStream_t stream) {
    const float* A = (const float*)d_in[0];
    const float* P = (const float*)d_in[1];
    float* out = (float*)d_out;

    const size_t BF_BYTES = (size_t)N_ROWS * D_DIM * sizeof(__hip_bfloat16); // 6291456
    const size_t V_BYTES  = (size_t)N_ROWS * sizeof(float);                  // 16384
    const size_t NEED = 2 * BF_BYTES + 4 * V_BYTES;

    if (ws_size >= NEED) {
        char* ws = (char*)d_ws;
        __hip_bfloat16* Ab = (__hip_bfloat16*)(ws);
        __hip_bfloat16* Pb = (__hip_bfloat16*)(ws + BF_BYTES);
        float* a2 = (float*)(ws + 2 * BF_BYTES);
        float* p2 = (float*)(ws + 2 * BF_BYTES + V_BYTES);
        float* S  = (float*)(ws + 2 * BF_BYTES + 2 * V_BYTES);
        float* Dd = (float*)(ws + 2 * BF_BYTES + 3 * V_BYTES);

        hipLaunchKernelGGL(cvt_norms, dim3(N_ROWS / 4, 2), dim3(256), 0, stream,
                           A, P, Ab, Pb, a2, p2, S);
        hipLaunchKernelGGL(gemm_fused, dim3(GRID_DIM, GRID_DIM), dim3(256), 0, stream,
                           Ab, Pb, a2, p2, S, Dd);
        hipLaunchKernelGGL(finalize, dim3(1), dim3(256), 0, stream, S, Dd, out);
    } else {
        hipLaunchKernelGGL(zero_out1, dim3(1), dim3(64), 0, stream, out);
        hipLaunchKernelGGL(naive_row, dim3(N_ROWS), dim3(256), 0, stream, A, P, out);
    }
}